// Round 1
// baseline (537.582 us; speedup 1.0000x reference)
//
#include <hip/hip_runtime.h>
#include <math.h>

#define TAU_F 32.0f

// -------------------- Kernel A: G[180][2048] = [M@Wt ; M@Wd] --------------------
// M[dm][e] = memory_tables[category[dm/10]][dm%10][e], dm in [0,90)
// G[dm][k]       = sum_e M[dm][e] * Wt[e][k]   (rows 0..89)
// G[90+dm][k]    = sum_e M[dm][e] * Wd[e][k]   (rows 90..179)
__global__ __launch_bounds__(256) void compute_g_kernel(
    const float* __restrict__ Wt, const float* __restrict__ Wd,
    const float* __restrict__ mem, const int* __restrict__ cat,
    float* __restrict__ G)
{
    __shared__ float Ml[6][768];
    const int bm  = blockIdx.x;      // 0..239
    const int mat = bm / 120;        // 0: topic, 1: domain
    const int rem = bm - mat * 120;
    const int rg  = rem >> 3;        // 0..14  (6-row group)
    const int cg  = rem & 7;         // 0..7   (256-col group)
    const int tid = threadIdx.x;

    for (int i = tid; i < 6 * 768; i += 256) {
        const int r  = i / 768;
        const int e  = i - r * 768;
        const int dm = rg * 6 + r;           // 0..89
        const int d  = dm / 10;
        const int m  = dm - d * 10;
        const int row = cat[d];
        Ml[r][e] = mem[((size_t)row * 10 + m) * 768 + e];
    }
    __syncthreads();

    const float* __restrict__ W = mat ? Wd : Wt;
    const int c = cg * 256 + tid;
    float acc[6] = {0.f, 0.f, 0.f, 0.f, 0.f, 0.f};
    for (int e = 0; e < 768; e += 4) {
        const float w0 = W[(size_t)(e + 0) * 2048 + c];
        const float w1 = W[(size_t)(e + 1) * 2048 + c];
        const float w2 = W[(size_t)(e + 2) * 2048 + c];
        const float w3 = W[(size_t)(e + 3) * 2048 + c];
        #pragma unroll
        for (int r = 0; r < 6; ++r) {
            acc[r] = fmaf(Ml[r][e + 0], w0, acc[r]);
            acc[r] = fmaf(Ml[r][e + 1], w1, acc[r]);
            acc[r] = fmaf(Ml[r][e + 2], w2, acc[r]);
            acc[r] = fmaf(Ml[r][e + 3], w3, acc[r]);
        }
    }
    #pragma unroll
    for (int r = 0; r < 6; ++r)
        G[(size_t)(mat * 90 + rg * 6 + r) * 2048 + c] = acc[r];
}

// -------------------- Kernel B: fused scores + softmax epilogue --------------------
// Per block: 64 feature rows; C = feat(64x2048) . G^T(2048x180), plus sum(x^2),
// then topic-softmax / domain-softmax epilogue -> out[64][9]
#define KC 32
#define FSTR 72    // feat LDS stride (64 rows + pad; 288B = 16B aligned, <=2-way banks)
#define CPAD 193   // G/scores LDS stride (192 cols + 1; odd => conflict-free)

__global__ __launch_bounds__(256) void fused_kernel(
    const float* __restrict__ feat, const float* __restrict__ G,
    float* __restrict__ out)
{
    __shared__ float smem[64 * CPAD];    // loop: featl[KC][FSTR] + gl[KC][CPAD]; then scores[64][CPAD]
    __shared__ float ssql[4][64];
    float* featl = smem;                 // [KC][FSTR]
    float* gl    = smem + KC * FSTR;     // [KC][CPAD]

    const int tid   = threadIdx.x;
    const int row0  = blockIdx.x * 64;
    const int ct    = tid & 31;          // col-thread 0..31
    const int rt    = tid >> 5;          // row-thread 0..7
    const int rbase = rt * 8;

    const int ka = tid & 7;              // k-quad for staging
    const int rr = tid >> 3;             // 0..31
    const int rs = tid & 63;             // ssq row
    const int qq = tid >> 6;             // ssq quarter

    float acc[8][6];
    #pragma unroll
    for (int i = 0; i < 8; ++i)
        #pragma unroll
        for (int j = 0; j < 6; ++j) acc[i][j] = 0.f;
    float ssq = 0.f;

    for (int ko = 0; ko < 2048; ko += KC) {
        // stage feat: 64 rows x KC k -> featl[k][r] (transposed)
        #pragma unroll
        for (int p = 0; p < 2; ++p) {
            const int r = rr + 32 * p;
            const float4 v = *(const float4*)&feat[(size_t)(row0 + r) * 2048 + ko + 4 * ka];
            const int kl = 4 * ka;
            featl[(kl + 0) * FSTR + r] = v.x;
            featl[(kl + 1) * FSTR + r] = v.y;
            featl[(kl + 2) * FSTR + r] = v.z;
            featl[(kl + 3) * FSTR + r] = v.w;
        }
        // stage G: 192 cols x KC k -> gl[k][c] (transposed, pad cols 180..191 = 0)
        #pragma unroll
        for (int p = 0; p < 6; ++p) {
            const int cc = rr + 32 * p;
            float4 v = make_float4(0.f, 0.f, 0.f, 0.f);
            if (cc < 180) v = *(const float4*)&G[(size_t)cc * 2048 + ko + 4 * ka];
            const int kl = 4 * ka;
            gl[(kl + 0) * CPAD + cc] = v.x;
            gl[(kl + 1) * CPAD + cc] = v.y;
            gl[(kl + 2) * CPAD + cc] = v.z;
            gl[(kl + 3) * CPAD + cc] = v.w;
        }
        __syncthreads();

        #pragma unroll 4
        for (int k = 0; k < KC; ++k) {
            const float4 a0 = *(const float4*)&featl[k * FSTR + rbase];
            const float4 a1 = *(const float4*)&featl[k * FSTR + rbase + 4];
            float b[6];
            #pragma unroll
            for (int j = 0; j < 6; ++j) b[j] = gl[k * CPAD + ct + 32 * j];
            const float a[8] = {a0.x, a0.y, a0.z, a0.w, a1.x, a1.y, a1.z, a1.w};
            #pragma unroll
            for (int i = 0; i < 8; ++i)
                #pragma unroll
                for (int j = 0; j < 6; ++j)
                    acc[i][j] = fmaf(a[i], b[j], acc[i][j]);
        }
        // fused sum of squares over this chunk (each (k,r) counted exactly once)
        #pragma unroll
        for (int jj = 0; jj < 8; ++jj) {
            const float x = featl[(qq * 8 + jj) * FSTR + rs];
            ssq = fmaf(x, x, ssq);
        }
        __syncthreads();
    }

    // dump raw scores to LDS: scores[r][c], c in [0,180) valid
    #pragma unroll
    for (int i = 0; i < 8; ++i)
        #pragma unroll
        for (int j = 0; j < 6; ++j)
            smem[(size_t)(rbase + i) * CPAD + ct + 32 * j] = acc[i][j];
    ssql[qq][rs] = ssq;
    __syncthreads();

    // epilogue: one thread per row
    if (tid < 64) {
        const int r = tid;
        const float nsq  = ssql[0][r] + ssql[1][r] + ssql[2][r] + ssql[3][r];
        const float inv  = TAU_F / fmaxf(sqrtf(nsq), 1e-12f);   // TAU / ||feat||
        const float* sc  = &smem[(size_t)r * CPAD];
        float lg[9];
        float dmax = -1e30f;
        #pragma unroll
        for (int d = 0; d < 9; ++d) {
            const float* v = sc + d * 10;        // topic raw dots
            const float* u = sc + 90 + d * 10;   // domain raw dots
            float mx = v[0];
            #pragma unroll
            for (int m = 1; m < 10; ++m) mx = fmaxf(mx, v[m]);
            float s = 0.f, dot = 0.f;
            #pragma unroll
            for (int m = 0; m < 10; ++m) {
                const float p = __expf((v[m] - mx) * inv);   // topic softmax (shift-invariant)
                s += p;
                dot = fmaf(p, u[m], dot);
            }
            const float l = (dot / s) * inv;     // TAU * sum_m att * (mem.dproj)
            lg[d] = l;
            dmax = fmaxf(dmax, l);
        }
        float s2 = 0.f;
        #pragma unroll
        for (int d = 0; d < 9; ++d) { const float p = __expf(lg[d] - dmax); lg[d] = p; s2 += p; }
        const float r2 = 1.0f / s2;
        #pragma unroll
        for (int d = 0; d < 9; ++d)
            out[(size_t)(row0 + r) * 9 + d] = lg[d] * r2;
    }
}

extern "C" void kernel_launch(void* const* d_in, const int* in_sizes, int n_in,
                              void* d_out, int out_size, void* d_ws, size_t ws_size,
                              hipStream_t stream) {
    const float* feature = (const float*)d_in[0];
    const float* Wt      = (const float*)d_in[1];
    const float* Wd      = (const float*)d_in[2];
    const float* mem     = (const float*)d_in[3];
    const int*   cat     = (const int*)d_in[4];
    float* G   = (float*)d_ws;            // 180 x 2048 f32 = 1.47 MB
    float* out = (float*)d_out;           // 16384 x 9 f32

    compute_g_kernel<<<240, 256, 0, stream>>>(Wt, Wd, mem, cat, G);
    fused_kernel<<<16384 / 64, 256, 0, stream>>>(feature, G, out);
}

// Round 2
// 394.600 us; speedup vs baseline: 1.3623x; 1.3623x over previous
//
#include <hip/hip_runtime.h>
#include <math.h>

#define TAU_F 32.0f

typedef __attribute__((ext_vector_type(8))) short bf16x8;
typedef __attribute__((ext_vector_type(4))) float f32x4;

__device__ __forceinline__ unsigned short bf16_rne(float x) {
    unsigned int u = __float_as_uint(x);
    u += 0x7fff + ((u >> 16) & 1);
    return (unsigned short)(u >> 16);
}
__device__ __forceinline__ float bf16f(unsigned short h) {
    return __uint_as_float(((unsigned int)h) << 16);
}

// -------------------- Kernel Z: zero G (ws is poisoned 0xAA each call) --------------------
__global__ __launch_bounds__(256) void zero_g(float4* __restrict__ g) {
    // 192*2048 floats = 98304 float4
    for (int i = blockIdx.x * 256 + threadIdx.x; i < 98304; i += 96 * 256)
        g[i] = make_float4(0.f, 0.f, 0.f, 0.f);
}

// -------------------- Kernel A1: G[192][2048] fp32 via ksplit atomics --------------------
// Row layout: 0..89 topic, 90..95 zero pad, 96..185 domain, 186..191 zero pad.
// grid = ksplit(6) x mat(2) x rowgroup(3 of 32) x coltile(8 of 256) = 288 blocks
__global__ __launch_bounds__(256) void gproj_kernel(
    const float* __restrict__ Wt, const float* __restrict__ Wd,
    const float* __restrict__ mem, const int* __restrict__ cat,
    float* __restrict__ G)
{
    __shared__ float Ml[32 * 132];   // [32 rows][128 e + pad]
    __shared__ float wl[16 * 260];   // [16 e][256 c + pad]

    const int bid = blockIdx.x;
    const int ks  = bid / 48;
    int rem = bid - ks * 48;
    const int mat = rem / 24; rem -= mat * 24;
    const int rg  = rem >> 3;        // 0..2
    const int ct  = rem & 7;         // 0..7
    const int tid = threadIdx.x;
    const int rt  = tid >> 5;        // 0..7
    const int ctn = tid & 31;        // 0..31
    const float* __restrict__ W = mat ? Wd : Wt;
    const int e0 = ks * 128;

    // stage M rows [rg*32, rg*32+32) x e [e0, e0+128)
    #pragma unroll
    for (int p = 0; p < 4; ++p) {
        const int fidx = tid + 256 * p;       // 0..1023 (float4 units)
        const int r    = fidx >> 5;           // 0..31
        const int ec   = (fidx & 31) * 4;     // 0..124
        const int dm   = rg * 32 + r;
        float4 v = make_float4(0.f, 0.f, 0.f, 0.f);
        if (dm < 90) {
            const int d    = dm / 10;
            const int mrow = cat[d] * 10 + (dm - d * 10);
            v = *(const float4*)(mem + (size_t)mrow * 768 + e0 + ec);
        }
        *(float4*)(Ml + r * 132 + ec) = v;
    }

    float acc[4][8];
    #pragma unroll
    for (int i = 0; i < 4; ++i)
        #pragma unroll
        for (int k = 0; k < 8; ++k) acc[i][k] = 0.f;

    for (int ch = 0; ch < 8; ++ch) {
        __syncthreads();   // protects Ml (first iter) / wl reuse (later iters)
        #pragma unroll
        for (int p = 0; p < 4; ++p) {
            const int fidx = tid + 256 * p;   // 0..1023
            const int er   = fidx >> 6;       // 0..15
            const int cc   = (fidx & 63) * 4; // 0..252
            *(float4*)(wl + er * 260 + cc) =
                *(const float4*)(W + (size_t)(e0 + ch * 16 + er) * 2048 + ct * 256 + cc);
        }
        __syncthreads();

        #pragma unroll
        for (int eg = 0; eg < 4; ++eg) {
            float4 m4[4], wA[4], wB[4];
            #pragma unroll
            for (int i = 0; i < 4; ++i)
                m4[i] = *(const float4*)(Ml + (rt * 4 + i) * 132 + ch * 16 + eg * 4);
            #pragma unroll
            for (int q = 0; q < 4; ++q) {
                wA[q] = *(const float4*)(wl + (eg * 4 + q) * 260 + ctn * 4);
                wB[q] = *(const float4*)(wl + (eg * 4 + q) * 260 + 128 + ctn * 4);
            }
            #pragma unroll
            for (int i = 0; i < 4; ++i) {
                const float mv[4] = {m4[i].x, m4[i].y, m4[i].z, m4[i].w};
                #pragma unroll
                for (int q = 0; q < 4; ++q) {
                    acc[i][0] = fmaf(mv[q], wA[q].x, acc[i][0]);
                    acc[i][1] = fmaf(mv[q], wA[q].y, acc[i][1]);
                    acc[i][2] = fmaf(mv[q], wA[q].z, acc[i][2]);
                    acc[i][3] = fmaf(mv[q], wA[q].w, acc[i][3]);
                    acc[i][4] = fmaf(mv[q], wB[q].x, acc[i][4]);
                    acc[i][5] = fmaf(mv[q], wB[q].y, acc[i][5]);
                    acc[i][6] = fmaf(mv[q], wB[q].z, acc[i][6]);
                    acc[i][7] = fmaf(mv[q], wB[q].w, acc[i][7]);
                }
            }
        }
    }

    const int growb = mat * 96 + rg * 32 + rt * 4;
    #pragma unroll
    for (int i = 0; i < 4; ++i) {
        float* gr = G + (size_t)(growb + i) * 2048 + ct * 256 + ctn * 4;
        #pragma unroll
        for (int k = 0; k < 4; ++k) {
            atomicAdd(gr + k, acc[i][k]);
            atomicAdd(gr + 128 + k, acc[i][4 + k]);
        }
    }
}

// -------------------- Kernel A2: split G fp32 -> bf16 hi/lo planes --------------------
__global__ __launch_bounds__(256) void split_g(const float* __restrict__ G,
                                               unsigned short* __restrict__ gH,
                                               unsigned short* __restrict__ gL)
{
    const int idx = blockIdx.x * 256 + threadIdx.x;    // 0..49151 (8-elem units)
    const float4 a = *(const float4*)(G + (size_t)idx * 8);
    const float4 b = *(const float4*)(G + (size_t)idx * 8 + 4);
    const float xs[8] = {a.x, a.y, a.z, a.w, b.x, b.y, b.z, b.w};
    union { unsigned short s[8]; uint4 v; } ph, pl;
    #pragma unroll
    for (int j = 0; j < 8; ++j) {
        const unsigned short hh = bf16_rne(xs[j]);
        ph.s[j] = hh;
        pl.s[j] = bf16_rne(xs[j] - bf16f(hh));
    }
    *(uint4*)(gH + (size_t)idx * 8) = ph.v;
    *(uint4*)(gL + (size_t)idx * 8) = pl.v;
}

// -------------------- Kernel B: split-bf16 MFMA GEMM + fused softmax epilogue ---------
// Block: 64 feat rows x 192 G rows, K=2048 in chunks of 32. 4 waves, wave w owns
// N-cols [w*48, w*48+48) as 3 16-wide tiles x 4 M-tiles. 3-pass split bf16.
#define SPAD 196

__global__ __launch_bounds__(256) void fused_mfma(
    const float* __restrict__ feat,
    const unsigned short* __restrict__ gH, const unsigned short* __restrict__ gL,
    float* __restrict__ out)
{
    __shared__ __align__(16) char smem_raw[50176];   // staging (40960) U scores (50176)
    __shared__ float ssql[4][64];
    unsigned short* aHl = (unsigned short*)smem_raw;     // [64][40]
    unsigned short* aLl = aHl + 64 * 40;
    unsigned short* gHl = aLl + 64 * 40;                 // [192][40]
    unsigned short* gLl = gHl + 192 * 40;
    float* scores = (float*)smem_raw;                    // [64][SPAD]

    const int tid  = threadIdx.x;
    const int row0 = blockIdx.x * 64;
    const int w  = tid >> 6, l = tid & 63;
    const int lm = l & 15,  lq = l >> 4;

    const int sr = tid >> 2;          // staged feat row 0..63
    const int sk = (tid & 3) * 8;     // k-offset in chunk

    f32x4 acc[4][3];
    #pragma unroll
    for (int i = 0; i < 4; ++i)
        #pragma unroll
        for (int j = 0; j < 3; ++j) acc[i][j] = (f32x4)0.f;
    float ssq = 0.f;

    const float* fptr = feat + (size_t)(row0 + sr) * 2048 + sk;

    // prefetch chunk 0
    float4 f0 = *(const float4*)(fptr);
    float4 f1 = *(const float4*)(fptr + 4);
    uint4 ghv[3], glv[3];
    #pragma unroll
    for (int p = 0; p < 3; ++p) {
        const int idx  = tid + 256 * p;          // 0..767
        const int grow = idx >> 2;               // 0..191
        const int gk   = (idx & 3) * 8;
        ghv[p] = *(const uint4*)(gH + (size_t)grow * 2048 + gk);
        glv[p] = *(const uint4*)(gL + (size_t)grow * 2048 + gk);
    }

    for (int kc = 0; kc < 64; ++kc) {
        // ---- stage current chunk into LDS (fp32 -> hi/lo bf16), fused ssq ----
        {
            const float xs[8] = {f0.x, f0.y, f0.z, f0.w, f1.x, f1.y, f1.z, f1.w};
            union { unsigned short s[8]; uint4 v; } ph, pl;
            #pragma unroll
            for (int j = 0; j < 8; ++j) {
                const float x = xs[j];
                ssq = fmaf(x, x, ssq);
                const unsigned short hh = bf16_rne(x);
                ph.s[j] = hh;
                pl.s[j] = bf16_rne(x - bf16f(hh));
            }
            *(uint4*)(aHl + sr * 40 + sk) = ph.v;
            *(uint4*)(aLl + sr * 40 + sk) = pl.v;
        }
        #pragma unroll
        for (int p = 0; p < 3; ++p) {
            const int idx  = tid + 256 * p;
            const int grow = idx >> 2;
            const int gk   = (idx & 3) * 8;
            *(uint4*)(gHl + grow * 40 + gk) = ghv[p];
            *(uint4*)(gLl + grow * 40 + gk) = glv[p];
        }
        __syncthreads();

        // ---- prefetch next chunk (overlaps with MFMA below) ----
        const int kn = (kc < 63 ? kc + 1 : 63) * 32;
        f0 = *(const float4*)(fptr + kn);
        f1 = *(const float4*)(fptr + kn + 4);
        #pragma unroll
        for (int p = 0; p < 3; ++p) {
            const int idx  = tid + 256 * p;
            const int grow = idx >> 2;
            const int gk   = (idx & 3) * 8;
            ghv[p] = *(const uint4*)(gH + (size_t)grow * 2048 + kn + gk);
            glv[p] = *(const uint4*)(gL + (size_t)grow * 2048 + kn + gk);
        }

        // ---- MFMA: 3-pass split bf16 ----
        bf16x8 fa[4], fl[4], gb[3], gbl[3];
        #pragma unroll
        for (int i = 0; i < 4; ++i) {
            fa[i] = *(const bf16x8*)(aHl + (i * 16 + lm) * 40 + lq * 8);
            fl[i] = *(const bf16x8*)(aLl + (i * 16 + lm) * 40 + lq * 8);
        }
        #pragma unroll
        for (int j = 0; j < 3; ++j) {
            const int n = w * 48 + j * 16 + lm;
            gb[j]  = *(const bf16x8*)(gHl + n * 40 + lq * 8);
            gbl[j] = *(const bf16x8*)(gLl + n * 40 + lq * 8);
        }
        #pragma unroll
        for (int i = 0; i < 4; ++i)
            #pragma unroll
            for (int j = 0; j < 3; ++j) {
                acc[i][j] = __builtin_amdgcn_mfma_f32_16x16x32_bf16(fa[i], gb[j],  acc[i][j], 0, 0, 0);
                acc[i][j] = __builtin_amdgcn_mfma_f32_16x16x32_bf16(fa[i], gbl[j], acc[i][j], 0, 0, 0);
                acc[i][j] = __builtin_amdgcn_mfma_f32_16x16x32_bf16(fl[i], gb[j],  acc[i][j], 0, 0, 0);
            }
        __syncthreads();
    }

    // ---- dump scores to LDS (D layout: row = lq*4+r, col = lm) ----
    #pragma unroll
    for (int i = 0; i < 4; ++i)
        #pragma unroll
        for (int j = 0; j < 3; ++j)
            #pragma unroll
            for (int r = 0; r < 4; ++r)
                scores[(i * 16 + lq * 4 + r) * SPAD + w * 48 + j * 16 + lm] = acc[i][j][r];
    ssql[tid & 3][sr] = ssq;
    __syncthreads();

    // ---- epilogue: one thread per row ----
    if (tid < 64) {
        const int r = tid;
        const float nsq = ssql[0][r] + ssql[1][r] + ssql[2][r] + ssql[3][r];
        const float inv = TAU_F / fmaxf(sqrtf(nsq), 1e-12f);
        const float* sc = scores + r * SPAD;
        float lg[9];
        float dmax = -1e30f;
        #pragma unroll
        for (int d = 0; d < 9; ++d) {
            const float* v = sc + d * 10;          // topic rows 0..89
            const float* u = sc + 96 + d * 10;     // domain rows 96..185
            float mx = v[0];
            #pragma unroll
            for (int m = 1; m < 10; ++m) mx = fmaxf(mx, v[m]);
            float s = 0.f, dot = 0.f;
            #pragma unroll
            for (int m = 0; m < 10; ++m) {
                const float p = __expf((v[m] - mx) * inv);
                s += p;
                dot = fmaf(p, u[m], dot);
            }
            const float lgt = (dot / s) * inv;
            lg[d] = lgt;
            dmax = fmaxf(dmax, lgt);
        }
        float s2 = 0.f;
        #pragma unroll
        for (int d = 0; d < 9; ++d) { const float p = __expf(lg[d] - dmax); lg[d] = p; s2 += p; }
        const float r2 = 1.0f / s2;
        #pragma unroll
        for (int d = 0; d < 9; ++d)
            out[(size_t)(row0 + r) * 9 + d] = lg[d] * r2;
    }
}

extern "C" void kernel_launch(void* const* d_in, const int* in_sizes, int n_in,
                              void* d_out, int out_size, void* d_ws, size_t ws_size,
                              hipStream_t stream) {
    const float* feature = (const float*)d_in[0];
    const float* Wt      = (const float*)d_in[1];
    const float* Wd      = (const float*)d_in[2];
    const float* mem     = (const float*)d_in[3];
    const int*   cat     = (const int*)d_in[4];

    float* G = (float*)d_ws;                                        // 192x2048 fp32
    unsigned short* gH = (unsigned short*)((char*)d_ws + (size_t)192 * 2048 * 4);
    unsigned short* gL = gH + (size_t)192 * 2048;
    float* out = (float*)d_out;

    zero_g<<<96, 256, 0, stream>>>((float4*)G);
    gproj_kernel<<<288, 256, 0, stream>>>(Wt, Wd, mem, cat, G);
    split_g<<<192, 256, 0, stream>>>(G, gH, gL);
    fused_mfma<<<256, 256, 0, stream>>>(feature, gH, gL, out);
}

// Round 3
// 287.591 us; speedup vs baseline: 1.8693x; 1.3721x over previous
//
#include <hip/hip_runtime.h>
#include <math.h>

#define TAU_F 32.0f

typedef __attribute__((ext_vector_type(8))) _Float16 half8;
typedef __attribute__((ext_vector_type(4))) float f32x4;

union HU { uint4 u; half8 v; };

// ============ Kernel 1: G partials, fp32 VALU, no atomics ============
// P[ks][192][2048], ks=4 (K-split of 768 into 192 each).
// G row layout: 0..89 topic, 90..95 zero, 96..185 domain, 186..191 zero.
// grid = mat(2) x ks(4) x coltile(32 of 64) = 256 blocks, 256 thr.
__global__ __launch_bounds__(256) void gproj2(
    const float* __restrict__ Wt, const float* __restrict__ Wd,
    const float* __restrict__ mem, const int* __restrict__ cat,
    float* __restrict__ P)
{
    __shared__ float Ml[96 * 36];   // [96 rows][32 k + pad]
    __shared__ float Wl[32 * 68];   // [32 k][64 c + pad]

    const int bid = blockIdx.x;
    const int mat = bid >> 7;
    const int ks  = (bid >> 5) & 3;
    const int ct  = bid & 31;
    const int c0  = ct * 64;
    const int tid = threadIdx.x;
    const float* __restrict__ W = mat ? Wd : Wt;

    const int tr = tid >> 4;   // 0..15 -> rows tr*6..tr*6+5
    const int tc = tid & 15;   // 0..15 -> cols tc*4..tc*4+3

    float acc[6][4];
    #pragma unroll
    for (int j = 0; j < 6; ++j)
        #pragma unroll
        for (int q = 0; q < 4; ++q) acc[j][q] = 0.f;

    for (int ch = 0; ch < 6; ++ch) {
        __syncthreads();
        // stage M rows (gathered via cat), 96x32, zeros for rows>=90
        #pragma unroll
        for (int p = 0; p < 3; ++p) {
            const int idx = tid + 256 * p;        // 0..767 float4 units
            const int r   = idx >> 3;             // 0..95
            const int kq  = idx & 7;
            float4 v = make_float4(0.f, 0.f, 0.f, 0.f);
            if (r < 90) {
                const int d = r / 10;
                const int mrow = cat[d] * 10 + (r - d * 10);
                v = *(const float4*)(mem + (size_t)mrow * 768 + ks * 192 + ch * 32 + kq * 4);
            }
            *(float4*)(Ml + r * 36 + kq * 4) = v;
        }
        // stage W tile 32x64
        #pragma unroll
        for (int p = 0; p < 2; ++p) {
            const int idx = tid + 256 * p;        // 0..511
            const int e   = idx >> 4;             // 0..31
            const int c4  = (idx & 15) * 4;
            *(float4*)(Wl + e * 68 + c4) =
                *(const float4*)(W + (size_t)(ks * 192 + ch * 32 + e) * 2048 + c0 + c4);
        }
        __syncthreads();

        #pragma unroll
        for (int e = 0; e < 32; e += 4) {
            float4 m4[6], w4[4];
            #pragma unroll
            for (int j = 0; j < 6; ++j) m4[j] = *(const float4*)(Ml + (tr * 6 + j) * 36 + e);
            #pragma unroll
            for (int q = 0; q < 4; ++q) w4[q] = *(const float4*)(Wl + (e + q) * 68 + tc * 4);
            #pragma unroll
            for (int j = 0; j < 6; ++j) {
                const float mv[4] = {m4[j].x, m4[j].y, m4[j].z, m4[j].w};
                #pragma unroll
                for (int q = 0; q < 4; ++q) {
                    acc[j][0] = fmaf(mv[q], w4[q].x, acc[j][0]);
                    acc[j][1] = fmaf(mv[q], w4[q].y, acc[j][1]);
                    acc[j][2] = fmaf(mv[q], w4[q].z, acc[j][2]);
                    acc[j][3] = fmaf(mv[q], w4[q].w, acc[j][3]);
                }
            }
        }
    }

    #pragma unroll
    for (int j = 0; j < 6; ++j) {
        float4 v = make_float4(acc[j][0], acc[j][1], acc[j][2], acc[j][3]);
        *(float4*)(P + (size_t)ks * 192 * 2048 + (size_t)(mat * 96 + tr * 6 + j) * 2048 + c0 + tc * 4) = v;
    }
}

// ============ Kernel 2: reduce partials, split to f16 hi/lo, fragment-major ============
// dst index for element (n, k): kc=k>>5, lq=(k>>3)&3, j=k&7 -> ((kc*4+lq)*192 + n)*8 + j
__global__ __launch_bounds__(256) void split_g2(
    const float* __restrict__ P,
    unsigned short* __restrict__ gH2, unsigned short* __restrict__ gL2)
{
    const int u  = blockIdx.x * 256 + threadIdx.x;  // 0..49151
    const int n  = u >> 8;
    const int k0 = (u & 255) * 8;

    float s[8] = {0.f, 0.f, 0.f, 0.f, 0.f, 0.f, 0.f, 0.f};
    #pragma unroll
    for (int ks = 0; ks < 4; ++ks) {
        const float4 a = *(const float4*)(P + (size_t)ks * 393216 + (size_t)n * 2048 + k0);
        const float4 b = *(const float4*)(P + (size_t)ks * 393216 + (size_t)n * 2048 + k0 + 4);
        s[0] += a.x; s[1] += a.y; s[2] += a.z; s[3] += a.w;
        s[4] += b.x; s[5] += b.y; s[6] += b.z; s[7] += b.w;
    }
    union { _Float16 h[8]; uint4 u4; } hi, lo;
    #pragma unroll
    for (int e = 0; e < 8; ++e) {
        const _Float16 h = (_Float16)s[e];
        hi.h[e] = h;
        lo.h[e] = (_Float16)(s[e] - (float)h);
    }
    const int kc = k0 >> 5, lq = (k0 >> 3) & 3;
    const size_t dst = ((size_t)(kc * 4 + lq) * 192 + n) * 8;
    *(uint4*)(gH2 + dst) = hi.u4;
    *(uint4*)(gL2 + dst) = lo.u4;
}

// ============ Kernel 3: barrier-free split-f16 MFMA GEMM + fused epilogue ============
// 512 thr (8 waves): kw=w&1 (K-chunks mod 2), nq=w>>2... nq=w>>1 (48-col slice).
// Per wave: 4 m-tiles x 3 n-tiles, 32 chunks of K=32. No __syncthreads in main loop.
#define SPAD 201

__global__ __launch_bounds__(512, 2) void fused_mfma2(
    const float* __restrict__ feat,
    const unsigned short* __restrict__ gH2, const unsigned short* __restrict__ gL2,
    float* __restrict__ out)
{
    __shared__ float scores[64 * SPAD];
    __shared__ float ssqp[2][64];

    const int tid  = threadIdx.x;
    const int row0 = blockIdx.x * 64;
    const int w  = tid >> 6, l = tid & 63;
    const int lm = l & 15,  lq = l >> 4;
    const int kw = w & 1,   nq = w >> 1;

    f32x4 acc[4][3];
    #pragma unroll
    for (int i = 0; i < 4; ++i)
        #pragma unroll
        for (int j = 0; j < 3; ++j) acc[i][j] = (f32x4)0.f;
    float ssq[4] = {0.f, 0.f, 0.f, 0.f};

    const float* aB[4];
    #pragma unroll
    for (int i = 0; i < 4; ++i)
        aB[i] = feat + (size_t)(row0 + i * 16 + lm) * 2048 + lq * 8;
    const int bbase = (nq * 48 + lm) * 8 + lq * 1536;   // + kc*6144 per chunk, + j*128 per tile

    // prefetch chunk kw
    float4 ar[4][2]; uint4 bh[3], bl[3];
    #pragma unroll
    for (int i = 0; i < 4; ++i) {
        ar[i][0] = *(const float4*)(aB[i] + kw * 32);
        ar[i][1] = *(const float4*)(aB[i] + kw * 32 + 4);
    }
    #pragma unroll
    for (int j = 0; j < 3; ++j) {
        const int off = bbase + kw * 6144 + j * 128;
        bh[j] = *(const uint4*)(gH2 + off);
        bl[j] = *(const uint4*)(gL2 + off);
    }

    for (int kc = kw; kc < 64; kc += 2) {
        // convert A fp32 -> f16 hi/lo frags (+ fused ssq on nq==0 waves)
        half8 fh[4], fl[4];
        #pragma unroll
        for (int i = 0; i < 4; ++i) {
            const float xs[8] = {ar[i][0].x, ar[i][0].y, ar[i][0].z, ar[i][0].w,
                                 ar[i][1].x, ar[i][1].y, ar[i][1].z, ar[i][1].w};
            union { _Float16 h[8]; half8 v; } uh, ul;
            #pragma unroll
            for (int e = 0; e < 8; ++e) {
                const float x = xs[e];
                const _Float16 h = (_Float16)x;
                uh.h[e] = h;
                ul.h[e] = (_Float16)(x - (float)h);
                if (nq == 0) ssq[i] = fmaf(x, x, ssq[i]);
            }
            fh[i] = uh.v; fl[i] = ul.v;
        }
        // issue next chunk's loads (overlap with MFMA)
        const int kn = (kc + 2 < 64) ? kc + 2 : kw;
        float4 arn[4][2]; uint4 bhn[3], bln[3];
        #pragma unroll
        for (int i = 0; i < 4; ++i) {
            arn[i][0] = *(const float4*)(aB[i] + kn * 32);
            arn[i][1] = *(const float4*)(aB[i] + kn * 32 + 4);
        }
        #pragma unroll
        for (int j = 0; j < 3; ++j) {
            const int off = bbase + kn * 6144 + j * 128;
            bhn[j] = *(const uint4*)(gH2 + off);
            bln[j] = *(const uint4*)(gL2 + off);
        }
        // 3-pass MFMA
        #pragma unroll
        for (int j = 0; j < 3; ++j) {
            HU h8, l8; h8.u = bh[j]; l8.u = bl[j];
            #pragma unroll
            for (int i = 0; i < 4; ++i) {
                acc[i][j] = __builtin_amdgcn_mfma_f32_16x16x32_f16(fh[i], h8.v, acc[i][j], 0, 0, 0);
                acc[i][j] = __builtin_amdgcn_mfma_f32_16x16x32_f16(fh[i], l8.v, acc[i][j], 0, 0, 0);
                acc[i][j] = __builtin_amdgcn_mfma_f32_16x16x32_f16(fl[i], h8.v, acc[i][j], 0, 0, 0);
            }
        }
        // rotate
        #pragma unroll
        for (int i = 0; i < 4; ++i) { ar[i][0] = arn[i][0]; ar[i][1] = arn[i][1]; }
        #pragma unroll
        for (int j = 0; j < 3; ++j) { bh[j] = bhn[j]; bl[j] = bln[j]; }
    }

    // ssq: reduce over lq (lanes xor 16, 32), nq==0 waves only
    if (nq == 0) {
        #pragma unroll
        for (int i = 0; i < 4; ++i) {
            ssq[i] += __shfl_xor(ssq[i], 16, 64);
            ssq[i] += __shfl_xor(ssq[i], 32, 64);
        }
        if (l < 16)
            #pragma unroll
            for (int i = 0; i < 4; ++i) ssqp[kw][i * 16 + lm] = ssq[i];
    }

    // scores: kw=0 writes, barrier, kw=1 adds (D layout: row=lq*4+r, col=lm)
    if (kw == 0) {
        #pragma unroll
        for (int i = 0; i < 4; ++i)
            #pragma unroll
            for (int j = 0; j < 3; ++j)
                #pragma unroll
                for (int r = 0; r < 4; ++r)
                    scores[(i * 16 + lq * 4 + r) * SPAD + nq * 48 + j * 16 + lm] = acc[i][j][r];
    }
    __syncthreads();
    if (kw == 1) {
        #pragma unroll
        for (int i = 0; i < 4; ++i)
            #pragma unroll
            for (int j = 0; j < 3; ++j)
                #pragma unroll
                for (int r = 0; r < 4; ++r)
                    scores[(i * 16 + lq * 4 + r) * SPAD + nq * 48 + j * 16 + lm] += acc[i][j][r];
    }
    __syncthreads();

    // epilogue: one thread per row
    if (tid < 64) {
        const int r = tid;
        const float nsq = ssqp[0][r] + ssqp[1][r];
        const float inv = TAU_F / fmaxf(sqrtf(nsq), 1e-12f);
        const float* sc = scores + r * SPAD;
        float lg[9];
        float dmax = -1e30f;
        #pragma unroll
        for (int d = 0; d < 9; ++d) {
            const float* v = sc + d * 10;          // topic rows 0..89
            const float* u = sc + 96 + d * 10;     // domain rows 96..185
            float mx = v[0];
            #pragma unroll
            for (int m = 1; m < 10; ++m) mx = fmaxf(mx, v[m]);
            float s = 0.f, dot = 0.f;
            #pragma unroll
            for (int m = 0; m < 10; ++m) {
                const float p = __expf((v[m] - mx) * inv);
                s += p;
                dot = fmaf(p, u[m], dot);
            }
            const float lgt = (dot / s) * inv;
            lg[d] = lgt;
            dmax = fmaxf(dmax, lgt);
        }
        float s2 = 0.f;
        #pragma unroll
        for (int d = 0; d < 9; ++d) { const float p = __expf(lg[d] - dmax); lg[d] = p; s2 += p; }
        const float r2 = 1.0f / s2;
        #pragma unroll
        for (int d = 0; d < 9; ++d)
            out[(size_t)(row0 + r) * 9 + d] = lg[d] * r2;
    }
}

extern "C" void kernel_launch(void* const* d_in, const int* in_sizes, int n_in,
                              void* d_out, int out_size, void* d_ws, size_t ws_size,
                              hipStream_t stream) {
    const float* feature = (const float*)d_in[0];
    const float* Wt      = (const float*)d_in[1];
    const float* Wd      = (const float*)d_in[2];
    const float* mem     = (const float*)d_in[3];
    const int*   cat     = (const int*)d_in[4];

    float* P = (float*)d_ws;                                            // 4 x 192 x 2048 f32 = 6.29 MB
    unsigned short* gH2 = (unsigned short*)((char*)d_ws + (size_t)4 * 192 * 2048 * 4);
    unsigned short* gL2 = gH2 + (size_t)192 * 2048;                     // +0.79 MB each
    float* out = (float*)d_out;

    gproj2<<<256, 256, 0, stream>>>(Wt, Wd, mem, cat, P);
    split_g2<<<192, 256, 0, stream>>>(P, gH2, gL2);
    fused_mfma2<<<256, 512, 0, stream>>>(feature, gH2, gL2, out);
}

// Round 4
// 268.193 us; speedup vs baseline: 2.0045x; 1.0723x over previous
//
#include <hip/hip_runtime.h>
#include <math.h>

#define TAU_F 32.0f

typedef __attribute__((ext_vector_type(8))) _Float16 half8;
typedef __attribute__((ext_vector_type(4))) float f32x4;

union HU { uint4 u; half8 v; };
union H4 { _Float16 h[4]; uint2 u2; };

// ============ Kernel 1: G partials, fp32 VALU, no atomics (unchanged from R3) ============
// P[ks][192][2048], ks=4. Rows: 0..89 topic, 90..95 zero, 96..185 domain, 186..191 zero.
__global__ __launch_bounds__(256) void gproj2(
    const float* __restrict__ Wt, const float* __restrict__ Wd,
    const float* __restrict__ mem, const int* __restrict__ cat,
    float* __restrict__ P)
{
    __shared__ float Ml[96 * 36];
    __shared__ float Wl[32 * 68];

    const int bid = blockIdx.x;
    const int mat = bid >> 7;
    const int ks  = (bid >> 5) & 3;
    const int ct  = bid & 31;
    const int c0  = ct * 64;
    const int tid = threadIdx.x;
    const float* __restrict__ W = mat ? Wd : Wt;

    const int tr = tid >> 4;
    const int tc = tid & 15;

    float acc[6][4];
    #pragma unroll
    for (int j = 0; j < 6; ++j)
        #pragma unroll
        for (int q = 0; q < 4; ++q) acc[j][q] = 0.f;

    for (int ch = 0; ch < 6; ++ch) {
        __syncthreads();
        #pragma unroll
        for (int p = 0; p < 3; ++p) {
            const int idx = tid + 256 * p;
            const int r   = idx >> 3;
            const int kq  = idx & 7;
            float4 v = make_float4(0.f, 0.f, 0.f, 0.f);
            if (r < 90) {
                const int d = r / 10;
                const int mrow = cat[d] * 10 + (r - d * 10);
                v = *(const float4*)(mem + (size_t)mrow * 768 + ks * 192 + ch * 32 + kq * 4);
            }
            *(float4*)(Ml + r * 36 + kq * 4) = v;
        }
        #pragma unroll
        for (int p = 0; p < 2; ++p) {
            const int idx = tid + 256 * p;
            const int e   = idx >> 4;
            const int c4  = (idx & 15) * 4;
            *(float4*)(Wl + e * 68 + c4) =
                *(const float4*)(W + (size_t)(ks * 192 + ch * 32 + e) * 2048 + c0 + c4);
        }
        __syncthreads();

        #pragma unroll
        for (int e = 0; e < 32; e += 4) {
            float4 m4[6], w4[4];
            #pragma unroll
            for (int j = 0; j < 6; ++j) m4[j] = *(const float4*)(Ml + (tr * 6 + j) * 36 + e);
            #pragma unroll
            for (int q = 0; q < 4; ++q) w4[q] = *(const float4*)(Wl + (e + q) * 68 + tc * 4);
            #pragma unroll
            for (int j = 0; j < 6; ++j) {
                const float mv[4] = {m4[j].x, m4[j].y, m4[j].z, m4[j].w};
                #pragma unroll
                for (int q = 0; q < 4; ++q) {
                    acc[j][0] = fmaf(mv[q], w4[q].x, acc[j][0]);
                    acc[j][1] = fmaf(mv[q], w4[q].y, acc[j][1]);
                    acc[j][2] = fmaf(mv[q], w4[q].z, acc[j][2]);
                    acc[j][3] = fmaf(mv[q], w4[q].w, acc[j][3]);
                }
            }
        }
    }

    #pragma unroll
    for (int j = 0; j < 6; ++j) {
        float4 v = make_float4(acc[j][0], acc[j][1], acc[j][2], acc[j][3]);
        *(float4*)(P + (size_t)ks * 393216 + (size_t)(mat * 96 + tr * 6 + j) * 2048 + c0 + tc * 4) = v;
    }
}

// ============ Kernel 2: reduce partials -> f16 hi/lo, FRAGMENT-MAJOR layout ============
// Fragment id f = (kc*12 + nq*3 + j)*2 + plane; within: lane l=lq*16+lm holds 8 halfs.
// addr(halfs) = f*512 + lq*128 + lm*8 + e.  (one wave fragment load = 1KB contiguous)
__global__ __launch_bounds__(256) void split_g3(
    const float* __restrict__ P, unsigned short* __restrict__ gB)
{
    const int u  = blockIdx.x * 256 + threadIdx.x;  // 0..49151
    const int n  = u >> 8;                          // 0..191
    const int k0 = (u & 255) * 8;                   // 0..2040

    float s[8] = {0.f, 0.f, 0.f, 0.f, 0.f, 0.f, 0.f, 0.f};
    #pragma unroll
    for (int ks = 0; ks < 4; ++ks) {
        const float4 a = *(const float4*)(P + (size_t)ks * 393216 + (size_t)n * 2048 + k0);
        const float4 b = *(const float4*)(P + (size_t)ks * 393216 + (size_t)n * 2048 + k0 + 4);
        s[0] += a.x; s[1] += a.y; s[2] += a.z; s[3] += a.w;
        s[4] += b.x; s[5] += b.y; s[6] += b.z; s[7] += b.w;
    }
    union { _Float16 h[8]; uint4 u4; } hi, lo;
    #pragma unroll
    for (int e = 0; e < 8; ++e) {
        const _Float16 h = (_Float16)s[e];
        hi.h[e] = h;
        lo.h[e] = (_Float16)(s[e] - (float)h);
    }
    const int kc = k0 >> 5;
    const int lq = (k0 >> 3) & 3;
    const int nq = n / 48;
    const int rm = n - nq * 48;
    const int j  = rm >> 4;
    const int lm = rm & 15;
    const size_t fH = (size_t)((kc * 12 + nq * 3 + j) * 2 + 0) * 512 + lq * 128 + lm * 8;
    const size_t fL = (size_t)((kc * 12 + nq * 3 + j) * 2 + 1) * 512 + lq * 128 + lm * 8;
    *(uint4*)(gB + fH) = hi.u4;
    *(uint4*)(gB + fL) = lo.u4;
}

// ============ Kernel 3: LDS-staged split-f16 MFMA + fused epilogue ============
// 512 blocks (M=32 rows each, 2 blocks/CU), 256 thr = 4 waves; wave nq owns 48 cols.
// A: coalesced fp32 load -> convert at staging -> LDS hi/lo (dbuf). B: 1KB fragment loads.
#define SPAD 196

__global__ __launch_bounds__(256, 2) void fused_mfma3(
    const float* __restrict__ feat, const unsigned short* __restrict__ gB,
    float* __restrict__ out)
{
    __shared__ __align__(16) char smem[25088];   // staging 10240 B  U  scores 25088 B
    __shared__ float ssqf[32];
    unsigned short* aS = (unsigned short*)smem;  // stage(buf,plane,row,k)=((buf*2+plane)*32+row)*40+k
    float* scores = (float*)smem;                // [32][SPAD]

    const int tid  = threadIdx.x;
    const int row0 = blockIdx.x * 32;
    const int nq = tid >> 6, l = tid & 63;
    const int lm = l & 15,  lq = l >> 4;

    const int srow = tid >> 3;        // staged row 0..31
    const int skq  = tid & 7;         // k-quad 0..7

    f32x4 acc[2][3];
    #pragma unroll
    for (int i = 0; i < 2; ++i)
        #pragma unroll
        for (int j = 0; j < 3; ++j) acc[i][j] = (f32x4)0.f;
    float ssq = 0.f;

    const float* fptr = feat + (size_t)(row0 + srow) * 2048 + skq * 4;

    // B fragment base for this wave: frag(kc,j,p) = (kc*12 + nq*3 + j)*2 + p
    const unsigned short* bptr = gB + (size_t)(nq * 3) * 2 * 512 + l * 8;
    // per (kc,j,p): offset = kc*12*512*? in halfs: kc stride = 12*1024? frag*512 halfs
    // addr = ((kc*12 + nq*3 + j)*2 + p)*512 + l*8  ->  bptr + kc*12288 + j*1024 + p*512

    // ---- prologue ----
    float4 fA  = *(const float4*)(fptr);           // chunk 0
    float4 fd1 = *(const float4*)(fptr + 32);      // chunk 1
    float4 fd2 = *(const float4*)(fptr + 64);      // chunk 2
    uint4 bh[3], bl[3];
    #pragma unroll
    for (int j = 0; j < 3; ++j) {
        bh[j] = *(const uint4*)(bptr + j * 1024);
        bl[j] = *(const uint4*)(bptr + j * 1024 + 512);
    }
    // convert chunk 0 -> buf 0
    {
        const float xs[4] = {fA.x, fA.y, fA.z, fA.w};
        H4 h, lo;
        #pragma unroll
        for (int e = 0; e < 4; ++e) {
            const float x = xs[e];
            ssq = fmaf(x, x, ssq);
            const _Float16 hh = (_Float16)x;
            h.h[e]  = hh;
            lo.h[e] = (_Float16)(x - (float)hh);
        }
        *(uint2*)(aS + (size_t)(0 * 32 + srow) * 40 + skq * 4) = h.u2;   // buf0 plane0
        *(uint2*)(aS + (size_t)(1 * 32 + srow) * 40 + skq * 4) = lo.u2;  // buf0 plane1
    }
    __syncthreads();

    for (int kc = 0; kc < 64; ++kc) {
        // issue feat load for kc+3 (distance 3 covers ~900cyc HBM latency)
        const int kf = (kc + 3 < 64) ? kc + 3 : 63;
        float4 fd3 = *(const float4*)(fptr + kf * 32);
        // issue B loads for kc+1
        const int kb = (kc + 1 < 64) ? kc + 1 : 63;
        uint4 bhn[3], bln[3];
        #pragma unroll
        for (int j = 0; j < 3; ++j) {
            bhn[j] = *(const uint4*)(bptr + (size_t)kb * 12288 + j * 1024);
            bln[j] = *(const uint4*)(bptr + (size_t)kb * 12288 + j * 1024 + 512);
        }

        // convert chunk kc+1 -> buf (kc+1)&1
        if (kc < 63) {
            const int nb = (kc + 1) & 1;
            const float xs[4] = {fd1.x, fd1.y, fd1.z, fd1.w};
            H4 h, lo;
            #pragma unroll
            for (int e = 0; e < 4; ++e) {
                const float x = xs[e];
                ssq = fmaf(x, x, ssq);
                const _Float16 hh = (_Float16)x;
                h.h[e]  = hh;
                lo.h[e] = (_Float16)(x - (float)hh);
            }
            *(uint2*)(aS + (size_t)((nb * 2 + 0) * 32 + srow) * 40 + skq * 4) = h.u2;
            *(uint2*)(aS + (size_t)((nb * 2 + 1) * 32 + srow) * 40 + skq * 4) = lo.u2;
        }

        // A fragments from LDS buf kc&1
        const int cb = kc & 1;
        half8 fh[2], fl[2];
        #pragma unroll
        for (int i = 0; i < 2; ++i) {
            HU t0, t1;
            t0.u = *(const uint4*)(aS + (size_t)((cb * 2 + 0) * 32 + i * 16 + lm) * 40 + lq * 8);
            t1.u = *(const uint4*)(aS + (size_t)((cb * 2 + 1) * 32 + i * 16 + lm) * 40 + lq * 8);
            fh[i] = t0.v; fl[i] = t1.v;
        }

        // 3-pass MFMA
        #pragma unroll
        for (int j = 0; j < 3; ++j) {
            HU h8, l8; h8.u = bh[j]; l8.u = bl[j];
            #pragma unroll
            for (int i = 0; i < 2; ++i) {
                acc[i][j] = __builtin_amdgcn_mfma_f32_16x16x32_f16(fh[i], h8.v, acc[i][j], 0, 0, 0);
                acc[i][j] = __builtin_amdgcn_mfma_f32_16x16x32_f16(fh[i], l8.v, acc[i][j], 0, 0, 0);
                acc[i][j] = __builtin_amdgcn_mfma_f32_16x16x32_f16(fl[i], h8.v, acc[i][j], 0, 0, 0);
            }
        }
        __syncthreads();

        // rotate
        fd1 = fd2; fd2 = fd3;
        #pragma unroll
        for (int j = 0; j < 3; ++j) { bh[j] = bhn[j]; bl[j] = bln[j]; }
    }

    // ssq reduce over the 8 k-quad threads of each row (low 3 lane bits)
    ssq += __shfl_xor(ssq, 1, 64);
    ssq += __shfl_xor(ssq, 2, 64);
    ssq += __shfl_xor(ssq, 4, 64);
    if ((tid & 7) == 0) ssqf[tid >> 3] = ssq;

    // scores to LDS (D layout: row = lq*4+r, col = lm)
    #pragma unroll
    for (int i = 0; i < 2; ++i)
        #pragma unroll
        for (int j = 0; j < 3; ++j)
            #pragma unroll
            for (int r = 0; r < 4; ++r)
                scores[(size_t)(i * 16 + lq * 4 + r) * SPAD + nq * 48 + j * 16 + lm] = acc[i][j][r];
    __syncthreads();

    // epilogue: one thread per row
    if (tid < 32) {
        const int r = tid;
        const float inv = TAU_F / fmaxf(sqrtf(ssqf[r]), 1e-12f);
        const float* sc = scores + (size_t)r * SPAD;
        float lg[9];
        float dmax = -1e30f;
        #pragma unroll
        for (int d = 0; d < 9; ++d) {
            const float* v = sc + d * 10;          // topic rows 0..89
            const float* u = sc + 96 + d * 10;     // domain rows 96..185
            float mx = v[0];
            #pragma unroll
            for (int m = 1; m < 10; ++m) mx = fmaxf(mx, v[m]);
            float s = 0.f, dot = 0.f;
            #pragma unroll
            for (int m = 0; m < 10; ++m) {
                const float p = __expf((v[m] - mx) * inv);
                s += p;
                dot = fmaf(p, u[m], dot);
            }
            const float lgt = (dot / s) * inv;
            lg[d] = lgt;
            dmax = fmaxf(dmax, lgt);
        }
        float s2 = 0.f;
        #pragma unroll
        for (int d = 0; d < 9; ++d) { const float p = __expf(lg[d] - dmax); lg[d] = p; s2 += p; }
        const float r2 = 1.0f / s2;
        #pragma unroll
        for (int d = 0; d < 9; ++d)
            out[(size_t)(row0 + r) * 9 + d] = lg[d] * r2;
    }
}

extern "C" void kernel_launch(void* const* d_in, const int* in_sizes, int n_in,
                              void* d_out, int out_size, void* d_ws, size_t ws_size,
                              hipStream_t stream) {
    const float* feature = (const float*)d_in[0];
    const float* Wt      = (const float*)d_in[1];
    const float* Wd      = (const float*)d_in[2];
    const float* mem     = (const float*)d_in[3];
    const int*   cat     = (const int*)d_in[4];

    float* P = (float*)d_ws;                                            // 4 x 192 x 2048 f32 = 6.29 MB
    unsigned short* gB = (unsigned short*)((char*)d_ws + (size_t)4 * 192 * 2048 * 4);  // 1.57 MB
    float* out = (float*)d_out;

    gproj2<<<256, 256, 0, stream>>>(Wt, Wd, mem, cat, P);
    split_g3<<<192, 256, 0, stream>>>(P, gB);
    fused_mfma3<<<512, 256, 0, stream>>>(feature, gB, out);
}

// Round 6
// 251.066 us; speedup vs baseline: 2.1412x; 1.0682x over previous
//
#include <hip/hip_runtime.h>
#include <math.h>

#define TAU_F 32.0f

typedef __attribute__((ext_vector_type(8))) _Float16 half8;
typedef __attribute__((ext_vector_type(2))) __fp16 half2v;
typedef __attribute__((ext_vector_type(4))) float f32x4;

union HU { uint4 u; half8 v; };

// ============ Kernel 1: G partials, fp32 VALU, no atomics (unchanged) ============
// P[ks][192][2048], ks=4. Rows: 0..89 topic, 90..95 zero, 96..185 domain, 186..191 zero.
__global__ __launch_bounds__(256) void gproj2(
    const float* __restrict__ Wt, const float* __restrict__ Wd,
    const float* __restrict__ mem, const int* __restrict__ cat,
    float* __restrict__ P)
{
    __shared__ float Ml[96 * 36];
    __shared__ float Wl[32 * 68];

    const int bid = blockIdx.x;
    const int mat = bid >> 7;
    const int ks  = (bid >> 5) & 3;
    const int ct  = bid & 31;
    const int c0  = ct * 64;
    const int tid = threadIdx.x;
    const float* __restrict__ W = mat ? Wd : Wt;

    const int tr = tid >> 4;
    const int tc = tid & 15;

    float acc[6][4];
    #pragma unroll
    for (int j = 0; j < 6; ++j)
        #pragma unroll
        for (int q = 0; q < 4; ++q) acc[j][q] = 0.f;

    for (int ch = 0; ch < 6; ++ch) {
        __syncthreads();
        #pragma unroll
        for (int p = 0; p < 3; ++p) {
            const int idx = tid + 256 * p;
            const int r   = idx >> 3;
            const int kq  = idx & 7;
            float4 v = make_float4(0.f, 0.f, 0.f, 0.f);
            if (r < 90) {
                const int d = r / 10;
                const int mrow = cat[d] * 10 + (r - d * 10);
                v = *(const float4*)(mem + (size_t)mrow * 768 + ks * 192 + ch * 32 + kq * 4);
            }
            *(float4*)(Ml + r * 36 + kq * 4) = v;
        }
        #pragma unroll
        for (int p = 0; p < 2; ++p) {
            const int idx = tid + 256 * p;
            const int e   = idx >> 4;
            const int c4  = (idx & 15) * 4;
            *(float4*)(Wl + e * 68 + c4) =
                *(const float4*)(W + (size_t)(ks * 192 + ch * 32 + e) * 2048 + c0 + c4);
        }
        __syncthreads();

        #pragma unroll
        for (int e = 0; e < 32; e += 4) {
            float4 m4[6], w4[4];
            #pragma unroll
            for (int j = 0; j < 6; ++j) m4[j] = *(const float4*)(Ml + (tr * 6 + j) * 36 + e);
            #pragma unroll
            for (int q = 0; q < 4; ++q) w4[q] = *(const float4*)(Wl + (e + q) * 68 + tc * 4);
            #pragma unroll
            for (int j = 0; j < 6; ++j) {
                const float mv[4] = {m4[j].x, m4[j].y, m4[j].z, m4[j].w};
                #pragma unroll
                for (int q = 0; q < 4; ++q) {
                    acc[j][0] = fmaf(mv[q], w4[q].x, acc[j][0]);
                    acc[j][1] = fmaf(mv[q], w4[q].y, acc[j][1]);
                    acc[j][2] = fmaf(mv[q], w4[q].z, acc[j][2]);
                    acc[j][3] = fmaf(mv[q], w4[q].w, acc[j][3]);
                }
            }
        }
    }

    #pragma unroll
    for (int j = 0; j < 6; ++j) {
        float4 v = make_float4(acc[j][0], acc[j][1], acc[j][2], acc[j][3]);
        *(float4*)(P + (size_t)ks * 393216 + (size_t)(mat * 96 + tr * 6 + j) * 2048 + c0 + tc * 4) = v;
    }
}

// ============ Kernel 2: reduce partials -> f16 hi/lo, fragment-major (unchanged) ============
// frag f = (kcg*12 + nq*3 + j)*2 + plane; addr = f*512 + lq*128 + lm*8
__global__ __launch_bounds__(256) void split_g3(
    const float* __restrict__ P, unsigned short* __restrict__ gB)
{
    const int u  = blockIdx.x * 256 + threadIdx.x;  // 0..49151
    const int n  = u >> 8;                          // 0..191
    const int k0 = (u & 255) * 8;                   // 0..2040

    float s[8] = {0.f, 0.f, 0.f, 0.f, 0.f, 0.f, 0.f, 0.f};
    #pragma unroll
    for (int ks = 0; ks < 4; ++ks) {
        const float4 a = *(const float4*)(P + (size_t)ks * 393216 + (size_t)n * 2048 + k0);
        const float4 b = *(const float4*)(P + (size_t)ks * 393216 + (size_t)n * 2048 + k0 + 4);
        s[0] += a.x; s[1] += a.y; s[2] += a.z; s[3] += a.w;
        s[4] += b.x; s[5] += b.y; s[6] += b.z; s[7] += b.w;
    }
    union { _Float16 h[8]; uint4 u4; } hi, lo;
    #pragma unroll
    for (int e = 0; e < 8; ++e) {
        const _Float16 h = (_Float16)s[e];
        hi.h[e] = h;
        lo.h[e] = (_Float16)(s[e] - (float)h);
    }
    const int kc = k0 >> 5;
    const int lq = (k0 >> 3) & 3;
    const int nq = n / 48;
    const int rm = n - nq * 48;
    const int j  = rm >> 4;
    const int lm = rm & 15;
    const size_t fH = (size_t)((kc * 12 + nq * 3 + j) * 2 + 0) * 512 + lq * 128 + lm * 8;
    const size_t fL = (size_t)((kc * 12 + nq * 3 + j) * 2 + 1) * 512 + lq * 128 + lm * 8;
    *(uint4*)(gB + fH) = hi.u4;
    *(uint4*)(gB + fL) = lo.u4;
}

// ============ Kernel 3: M=128 x K-split-4 split-f16 MFMA, partial scores out ============
// 512 blocks (rt=bid>>2 row-tile of 128, ks=bid&3 K-slice of 512), 256 thr = 4 waves (nq).
__global__ __launch_bounds__(256, 2) void fused_mfma4(
    const float* __restrict__ feat, const unsigned short* __restrict__ gB,
    float* __restrict__ P2, float* __restrict__ ssqp)
{
    __shared__ __align__(16) unsigned short aS[20480];  // [buf2][plane2][row128][40] = 40 KB

    const int tid = threadIdx.x;
    const int rt  = blockIdx.x >> 2;
    const int ks  = blockIdx.x & 3;
    const int row0 = rt * 128;

    const int w  = tid >> 6, l = tid & 63;
    const int lm = l & 15,  lq = l >> 4;
    const int r8 = tid >> 3, kq = tid & 7;

    f32x4 acc[8][3];
    #pragma unroll
    for (int i = 0; i < 8; ++i)
        #pragma unroll
        for (int j = 0; j < 3; ++j) acc[i][j] = (f32x4)0.f;
    float ssq4[4] = {0.f, 0.f, 0.f, 0.f};

    const float* fbase = feat + (size_t)(row0 + r8) * 2048 + ks * 512 + kq * 4;
    const unsigned short* bbase = gB + (size_t)ks * 196608 + (w * 3) * 1024 + l * 8;

    // ---- prologue ----
    float4 fa[4], fan[4];
    #pragma unroll
    for (int p = 0; p < 4; ++p) fa[p] = *(const float4*)(fbase + p * 65536);
    uint4 bh0[3], bl0[3], bh1[3], bl1[3];
    #pragma unroll
    for (int j = 0; j < 3; ++j) {
        bh0[j] = *(const uint4*)(bbase + j * 1024);
        bl0[j] = *(const uint4*)(bbase + j * 1024 + 512);
        bh1[j] = *(const uint4*)(bbase + 12288 + j * 1024);
        bl1[j] = *(const uint4*)(bbase + 12288 + j * 1024 + 512);
    }
    // convert chunk 0 -> buf 0
    #pragma unroll
    for (int p = 0; p < 4; ++p) {
        const float4 v = fa[p];
        ssq4[p] = fmaf(v.x, v.x, ssq4[p]); ssq4[p] = fmaf(v.y, v.y, ssq4[p]);
        ssq4[p] = fmaf(v.z, v.z, ssq4[p]); ssq4[p] = fmaf(v.w, v.w, ssq4[p]);
        half2v h01 = __builtin_amdgcn_cvt_pkrtz(v.x, v.y);
        half2v h23 = __builtin_amdgcn_cvt_pkrtz(v.z, v.w);
        half2v l01 = __builtin_amdgcn_cvt_pkrtz(v.x - (float)h01[0], v.y - (float)h01[1]);
        half2v l23 = __builtin_amdgcn_cvt_pkrtz(v.z - (float)h23[0], v.w - (float)h23[1]);
        union { half2v h2[2]; uint2 u2; } uh, ul;
        uh.h2[0] = h01; uh.h2[1] = h23;
        ul.h2[0] = l01; ul.h2[1] = l23;
        const int row = p * 32 + r8;
        *(uint2*)(aS + 0 * 5120 + row * 40 + kq * 4) = uh.u2;
        *(uint2*)(aS + 1 * 5120 + row * 40 + kq * 4) = ul.u2;
    }
    #pragma unroll
    for (int p = 0; p < 4; ++p) fan[p] = *(const float4*)(fbase + 32 + p * 65536);
    __syncthreads();

    #pragma unroll 2
    for (int kc = 0; kc < 16; ++kc) {
        // issue A + B loads for chunk kc+2 (clamped)
        const int kn = (kc + 2 < 16) ? kc + 2 : 15;
        float4 fa2[4];
        #pragma unroll
        for (int p = 0; p < 4; ++p) fa2[p] = *(const float4*)(fbase + kn * 32 + p * 65536);
        uint4 bh2[3], bl2[3];
        #pragma unroll
        for (int j = 0; j < 3; ++j) {
            bh2[j] = *(const uint4*)(bbase + (size_t)kn * 12288 + j * 1024);
            bl2[j] = *(const uint4*)(bbase + (size_t)kn * 12288 + j * 1024 + 512);
        }

        // convert chunk kc+1 -> buf (kc+1)&1
        if (kc < 15) {
            const int nb = (kc + 1) & 1;
            #pragma unroll
            for (int p = 0; p < 4; ++p) {
                const float4 v = fan[p];
                ssq4[p] = fmaf(v.x, v.x, ssq4[p]); ssq4[p] = fmaf(v.y, v.y, ssq4[p]);
                ssq4[p] = fmaf(v.z, v.z, ssq4[p]); ssq4[p] = fmaf(v.w, v.w, ssq4[p]);
                half2v h01 = __builtin_amdgcn_cvt_pkrtz(v.x, v.y);
                half2v h23 = __builtin_amdgcn_cvt_pkrtz(v.z, v.w);
                half2v l01 = __builtin_amdgcn_cvt_pkrtz(v.x - (float)h01[0], v.y - (float)h01[1]);
                half2v l23 = __builtin_amdgcn_cvt_pkrtz(v.z - (float)h23[0], v.w - (float)h23[1]);
                union { half2v h2[2]; uint2 u2; } uh, ul;
                uh.h2[0] = h01; uh.h2[1] = h23;
                ul.h2[0] = l01; ul.h2[1] = l23;
                const int row = p * 32 + r8;
                *(uint2*)(aS + (nb * 2 + 0) * 5120 + row * 40 + kq * 4) = uh.u2;
                *(uint2*)(aS + (nb * 2 + 1) * 5120 + row * 40 + kq * 4) = ul.u2;
            }
        }

        // MFMA on buf kc&1 with bh0/bl0
        const int cb = kc & 1;
        const unsigned short* aH = aS + (cb * 2 + 0) * 5120;
        const unsigned short* aL = aS + (cb * 2 + 1) * 5120;
        #pragma unroll
        for (int ih = 0; ih < 2; ++ih) {
            half8 fh[4], fl[4];
            #pragma unroll
            for (int i2 = 0; i2 < 4; ++i2) {
                const int row = (ih * 4 + i2) * 16 + lm;
                HU th, tl;
                th.u = *(const uint4*)(aH + row * 40 + lq * 8);
                tl.u = *(const uint4*)(aL + row * 40 + lq * 8);
                fh[i2] = th.v; fl[i2] = tl.v;
            }
            #pragma unroll
            for (int j = 0; j < 3; ++j) {
                HU h8, l8; h8.u = bh0[j]; l8.u = bl0[j];
                #pragma unroll
                for (int i2 = 0; i2 < 4; ++i2) {
                    const int i = ih * 4 + i2;
                    acc[i][j] = __builtin_amdgcn_mfma_f32_16x16x32_f16(fh[i2], h8.v, acc[i][j], 0, 0, 0);
                    acc[i][j] = __builtin_amdgcn_mfma_f32_16x16x32_f16(fh[i2], l8.v, acc[i][j], 0, 0, 0);
                    acc[i][j] = __builtin_amdgcn_mfma_f32_16x16x32_f16(fl[i2], h8.v, acc[i][j], 0, 0, 0);
                }
            }
        }
        __syncthreads();

        // rotate
        #pragma unroll
        for (int p = 0; p < 4; ++p) fan[p] = fa2[p];
        #pragma unroll
        for (int j = 0; j < 3; ++j) {
            bh0[j] = bh1[j]; bl0[j] = bl1[j];
            bh1[j] = bh2[j]; bl1[j] = bl2[j];
        }
    }

    // ssq partials: reduce over the 8 k-quad lanes of each row
    #pragma unroll
    for (int p = 0; p < 4; ++p) {
        float s = ssq4[p];
        s += __shfl_xor(s, 1, 64);
        s += __shfl_xor(s, 2, 64);
        s += __shfl_xor(s, 4, 64);
        if ((tid & 7) == 0) ssqp[(size_t)ks * 16384 + row0 + p * 32 + r8] = s;
    }

    // partial scores out (D layout: row = lq*4+r, col = lm)
    #pragma unroll
    for (int i = 0; i < 8; ++i)
        #pragma unroll
        for (int j = 0; j < 3; ++j)
            #pragma unroll
            for (int r = 0; r < 4; ++r)
                P2[((size_t)ks * 16384 + row0 + i * 16 + lq * 4 + r) * 192 + w * 48 + j * 16 + lm]
                    = acc[i][j][r];
}

// ============ Kernel 4: reduce K-split partials + softmax epilogue ============
#define EP_SPAD 196
__global__ __launch_bounds__(256) void ep_kernel(
    const float* __restrict__ P2, const float* __restrict__ ssqp,
    float* __restrict__ out)
{
    __shared__ float sc[64 * EP_SPAD];
    const int tid  = threadIdx.x;
    const int row0 = blockIdx.x * 64;

    float4 s[12];
    #pragma unroll
    for (int p = 0; p < 12; ++p) s[p] = make_float4(0.f, 0.f, 0.f, 0.f);
    #pragma unroll
    for (int ks = 0; ks < 4; ++ks)
        #pragma unroll
        for (int p = 0; p < 12; ++p) {
            const int u   = p * 256 + tid;
            const int row = u / 48;
            const int c4  = (u - row * 48) * 4;
            const float4 v = *(const float4*)(P2 + ((size_t)ks * 16384 + row0 + row) * 192 + c4);
            s[p].x += v.x; s[p].y += v.y; s[p].z += v.z; s[p].w += v.w;
        }
    #pragma unroll
    for (int p = 0; p < 12; ++p) {
        const int u   = p * 256 + tid;
        const int row = u / 48;
        const int c4  = (u - row * 48) * 4;
        *(float4*)(sc + row * EP_SPAD + c4) = s[p];
    }
    float nsq = 0.f;
    if (tid < 64) {
        nsq = ssqp[row0 + tid] + ssqp[16384 + row0 + tid]
            + ssqp[32768 + row0 + tid] + ssqp[49152 + row0 + tid];
    }
    __syncthreads();

    if (tid < 64) {
        const int r = tid;
        const float inv = TAU_F / fmaxf(sqrtf(nsq), 1e-12f);
        const float* scr = sc + (size_t)r * EP_SPAD;
        float lg[9];
        float dmax = -1e30f;
        #pragma unroll
        for (int d = 0; d < 9; ++d) {
            const float* v = scr + d * 10;          // topic rows 0..89
            const float* u = scr + 96 + d * 10;     // domain rows 96..185
            float mx = v[0];
            #pragma unroll
            for (int m = 1; m < 10; ++m) mx = fmaxf(mx, v[m]);
            float ssum = 0.f, dot = 0.f;
            #pragma unroll
            for (int m = 0; m < 10; ++m) {
                const float p = __expf((v[m] - mx) * inv);
                ssum += p;
                dot = fmaf(p, u[m], dot);
            }
            const float lgt = (dot / ssum) * inv;
            lg[d] = lgt;
            dmax = fmaxf(dmax, lgt);
        }
        float s2 = 0.f;
        #pragma unroll
        for (int d = 0; d < 9; ++d) { const float p = __expf(lg[d] - dmax); lg[d] = p; s2 += p; }
        const float r2 = 1.0f / s2;
        #pragma unroll
        for (int d = 0; d < 9; ++d)
            out[(size_t)(row0 + r) * 9 + d] = lg[d] * r2;
    }
}

extern "C" void kernel_launch(void* const* d_in, const int* in_sizes, int n_in,
                              void* d_out, int out_size, void* d_ws, size_t ws_size,
                              hipStream_t stream) {
    const float* feature = (const float*)d_in[0];
    const float* Wt      = (const float*)d_in[1];
    const float* Wd      = (const float*)d_in[2];
    const float* mem     = (const float*)d_in[3];
    const int*   cat     = (const int*)d_in[4];

    // ws layout (52.2 MB): P2 (50.33 MB, also aliases P's 6.3 MB — safe: P is dead
    // before fused_mfma4 writes P2, stream-ordered) | gB 1.57 MB | ssqp 256 KB
    float* P2 = (float*)d_ws;
    float* P  = (float*)d_ws;
    unsigned short* gB = (unsigned short*)((char*)d_ws + 50331648);
    float* ssqp = (float*)((char*)d_ws + 50331648 + 1572864);
    float* out = (float*)d_out;

    gproj2<<<256, 256, 0, stream>>>(Wt, Wd, mem, cat, P);
    split_g3<<<192, 256, 0, stream>>>(P, gB);
    fused_mfma4<<<512, 256, 0, stream>>>(feature, gB, P2, ssqp);
    ep_kernel<<<256, 256, 0, stream>>>(P2, ssqp, out);
}